// Round 6
// baseline (117.006 us; speedup 1.0000x reference)
//
#include <hip/hip_runtime.h>

#define T_STEPS 345
#define B_SZ    128
#define IN_SZ   13
#define H_SZ    128
#define OUT_SZ  9
#define XT      348                 // xst row pitch (floats)
#define CPAD    388                 // cur2 LDS row pitch (floats); 97 float4s/row
#define NBO     (B_SZ * OUT_SZ)    // 1152
#define CHUNK   92                  // layer-1 t-chunk (4 chunks: 92,92,92,69)
#define BUFR    104                 // cur1 buffer rows (CHUNK + 12 prefetch overrun)

// v7: concurrent serial chains. r5 lesson: scan1 (~15k cy) and scan2 (~15k cy)
// ran back-to-back in every prior version; they have no dependency at equal t,
// so run them on different waves with a ~1-chunk lag:
//   slot0: scan1 c0 | emit c1(w2-15)
//   slot1: scan1 c1 | emit c2(w2-13) | cur2 s0 (w14,w15)
//   slot2: scan1 c2 | emit c3(w2-13) | cur2 s1 (w14)    | scan2 s0 (w15)
//   slot3: scan1 c3 | cur2 s2,s3 (w2-13)                | scan2 s1 (w15)
//   slot4:            cur2 s4,s5 (w2-13)                | scan2 s2,s3 (w15)
//   slot5:                                                scan2 s4,s5+tail (w15)
// readfirstlane/s_load scalarization REVERTED (r5: pathological under profiler,
// -5us timed). All per-element arithmetic sequences BIT-IDENTICAL to passing v5.

__device__ __forceinline__ void emit_rows(float* __restrict__ buf,
                                          const float* __restrict__ xs,
                                          const float (&w1r)[IN_SZ], float b1r,
                                          int T0, int L, int h, int off, int stride)
{
    int tl = off;
    for (; tl + stride < L; tl += 2 * stride) {
        const int ta = T0 + tl, tb = T0 + tl + stride;
        float ca = b1r, cb = b1r;
#pragma unroll
        for (int c = 0; c < IN_SZ; ++c) {
            ca = fmaf(xs[c * XT + ta], w1r[c], ca);
            cb = fmaf(xs[c * XT + tb], w1r[c], cb);
        }
        buf[tl * H_SZ + h] = ca;
        buf[(tl + stride) * H_SZ + h] = cb;
    }
    if (tl < L) {
        const int ta = T0 + tl;
        float ca = b1r;
#pragma unroll
        for (int c = 0; c < IN_SZ; ++c) ca = fmaf(xs[c * XT + ta], w1r[c], ca);
        buf[tl * H_SZ + h] = ca;
    }
}

__device__ __forceinline__ void scan1_step(float& mem1, float u, float bt1, float th1,
                                           unsigned long long* __restrict__ msh,
                                           int t, bool sl, int half)
{
    mem1 = fmaf(bt1, mem1, u);
    const bool p = mem1 > th1;
    const unsigned long long m = __ballot(p);
    const float ms = mem1 - th1;            // == fmaf(-1, th1, mem1) bitwise
    mem1 = p ? ms : mem1;
    if (sl) msh[t * 2 + half] = m;
}

__device__ __forceinline__ void scan1_chunk(const float* __restrict__ buf,
                                            unsigned long long* __restrict__ msh,
                                            int T0, int L, int h,
                                            float bt1, float th1, float& mem1)
{
    const float* cb = buf + h;              // column h, row stride 128 floats
    const bool sl = (h & 63) == 0;
    const int half = h >> 6;
    // 12-row (3-group) rolling prefetch to cover LDS latency
    float a0 = cb[0*128], a1 = cb[1*128], a2 = cb[ 2*128], a3 = cb[ 3*128];
    float b0 = cb[4*128], b1v= cb[5*128], b2v= cb[ 6*128], b3 = cb[ 7*128];
    float c0 = cb[8*128], c1v= cb[9*128], c2v= cb[10*128], c3 = cb[11*128];
    const int fullg = L >> 2;
    const int rem   = L & 3;
    for (int g = 0; g < fullg; ++g) {
        const float u0 = a0, u1 = a1, u2 = a2, u3 = a3;
        a0 = b0; a1 = b1v; a2 = b2v; a3 = b3;
        b0 = c0; b1v = c1v; b2v = c2v; b3 = c3;
        const float* nb = cb + (g + 3) * 4 * 128;   // rows <= 103 < BUFR
        c0 = nb[0]; c1v = nb[128]; c2v = nb[256]; c3 = nb[384];
        const int tb = T0 + g * 4;
        scan1_step(mem1, u0, bt1, th1, msh, tb + 0, sl, half);
        scan1_step(mem1, u1, bt1, th1, msh, tb + 1, sl, half);
        scan1_step(mem1, u2, bt1, th1, msh, tb + 2, sl, half);
        scan1_step(mem1, u3, bt1, th1, msh, tb + 3, sl, half);
    }
    const int tb = T0 + fullg * 4;
    if (rem > 0) scan1_step(mem1, a0, bt1, th1, msh, tb + 0, sl, half);
    if (rem > 1) scan1_step(mem1, a1, bt1, th1, msh, tb + 1, sl, half);
    if (rem > 2) scan1_step(mem1, a2, bt1, th1, msh, tb + 2, sl, half);
}

// one (o, stripe) cur2 wave-task; h-chain 0..127 BIT-IDENTICAL to verified kernels
__device__ __forceinline__ void cur2_otask(int o, int s, int obase, int lane,
                                           const unsigned long long* __restrict__ msh,
                                           const float* __restrict__ W2,
                                           const float* __restrict__ b2,
                                           float* __restrict__ c2s)
{
    const int t  = s * 64 + lane;                             // < 384
    const int tc = (t < T_STEPS) ? t : (T_STEPS - 1);
    const uint4 mm = *(const uint4*)((const char*)msh + (size_t)tc * 16);
    const float* __restrict__ w2row = W2 + o * H_SZ;
    float acc = 0.0f;
#pragma unroll
    for (int h = 0; h < 32; ++h)
        acc = fmaf((float)((mm.x >> h) & 1u), w2row[h], acc);
#pragma unroll
    for (int h = 0; h < 32; ++h)
        acc = fmaf((float)((mm.y >> h) & 1u), w2row[32 + h], acc);
#pragma unroll
    for (int h = 0; h < 32; ++h)
        acc = fmaf((float)((mm.z >> h) & 1u), w2row[64 + h], acc);
#pragma unroll
    for (int h = 0; h < 32; ++h)
        acc = fmaf((float)((mm.w >> h) & 1u), w2row[96 + h], acc);
    c2s[(o - obase) * CPAD + t] = acc + b2[o];                // t<384<388 pad ok
}

// scan2 over one 64-step stripe (TAIL: guard tt<T_STEPS)
template<bool TAIL>
__device__ __forceinline__ void scan2_stripe(const float4* __restrict__ src4, int s,
                                             float bt2, float th2, float& mem2,
                                             float* __restrict__ out_spk,
                                             float* __restrict__ out_mem)
{
    const int sb = s * 16;
    float4 fA = src4[sb], fB = src4[sb + 1];
#pragma unroll
    for (int i = 0; i < 16; ++i) {
        const float4 u = fA; fA = fB; fB = src4[sb + i + 2];   // <=src4[97]: next-row over-read, discarded
        const float vv[4] = { u.x, u.y, u.z, u.w };
#pragma unroll
        for (int kk = 0; kk < 4; ++kk) {
            const int tt = s * 64 + i * 4 + kk;
            if (!TAIL || tt < T_STEPS) {
                mem2 = fmaf(bt2, mem2, vv[kk]);
                const bool p = mem2 > th2;
                const float s2 = p ? 1.0f : 0.0f;
                const float ms = mem2 - th2;     // == fmaf(-1, th2, mem2) bitwise
                mem2 = p ? ms : mem2;
                out_spk[(size_t)tt * NBO] = s2;
                out_mem[(size_t)tt * NBO] = mem2;
            }
        }
    }
}

__global__ __launch_bounds__(1024, 1)
void snn_fused(const float* __restrict__ x, const float* __restrict__ W1,
               const float* __restrict__ b1, const float* __restrict__ W2,
               const float* __restrict__ b2,
               const float* __restrict__ beta1p, const float* __restrict__ thr1p,
               const float* __restrict__ beta2p, const float* __restrict__ thr2p,
               float* __restrict__ out)
{
    const int b    = blockIdx.x >> 1;
    const int half = blockIdx.x & 1;
    const int tid  = threadIdx.x;
    const int wid  = tid >> 6;
    const int lane = tid & 63;
    const int hown = tid & 127;              // owned hidden neuron
    const int jsl  = tid >> 7;               // 0..7 time-slot group

    __shared__ __align__(16) float xst[IN_SZ * XT];              // 18,096 B
    __shared__ __align__(16) float cur1s[2][BUFR * H_SZ];        // 106,496 B
    __shared__ __align__(16) unsigned long long msh[352 * 2];    //  5,632 B
    __shared__ __align__(16) float c2s[OUT_SZ * CPAD];           // 13,968 B
    // total 144,192 B -> 1 block/CU, 16 waves/CU

    // hoist scalar params (cold-miss latency overlaps staging)
    const float bt1 = fminf(fmaxf(beta1p[0], 0.0f), 1.0f);
    const float th1 = thr1p[0];
    const float bt2 = fminf(fmaxf(beta2p[0], 0.0f), 1.0f);
    const float th2 = thr2p[0];

    // ---------------- phase 0: stage x[b] (c-major) and W1^T into LDS ----------------
    const float* xb = x + (size_t)b * (IN_SZ * T_STEPS);
    for (int i = tid; i < IN_SZ * T_STEPS; i += 1024) {
        const int c = i / T_STEPS;
        const int t = i - c * T_STEPS;
        xst[c * XT + t] = xb[i];             // lane-consecutive t: conflict-free
    }
    float* W1t = c2s;   // c2s free until cur2; holds W1t[c*128 + h]
    for (int i = tid; i < IN_SZ * H_SZ; i += 1024) {
        const int h = i / IN_SZ;
        const int c = i - IN_SZ * h;
        W1t[c * H_SZ + h] = W1[i];
    }
    __syncthreads();

    // ---------------- per-thread layer-1 weights (one h-row) ----------------
    float w1r[IN_SZ];
#pragma unroll
    for (int c = 0; c < IN_SZ; ++c) w1r[c] = W1t[c * H_SZ + hown];
    const float b1r = b1[hown];

    const int obase  = half ? 5 : 0;
    const int ntasks = half ? 4 : 5;
    const int L3     = T_STEPS - 3 * CHUNK;  // 69

    float mem1 = 0.0f;
    float mem2 = 0.0f;
    const int o_sc = obase + lane;                       // scanner's output row (wave 15)
    float* out_spk = out + (size_t)b * OUT_SZ + o_sc;
    float* out_mem = out_spk + (size_t)T_STEPS * NBO;
    const float4* src4 = (const float4*)(c2s + lane * CPAD);

    // pre: emit chunk 0 (all 16 waves, 8-way)
    emit_rows(cur1s[0], xst, w1r, b1r, 0, CHUNK, hown, jsl, 8);
    __syncthreads();

    // slot0: scan1 c0 | emit c1 (w2-15, 7-way)
    if (tid < 128)      scan1_chunk(cur1s[0], msh, 0, CHUNK, tid, bt1, th1, mem1);
    else                emit_rows(cur1s[1], xst, w1r, b1r, CHUNK, CHUNK, hown, jsl - 1, 7);
    __syncthreads();

    // slot1: scan1 c1 | emit c2 (w2-13, 6-way) | cur2 s0 (w14,w15)
    if (tid < 128)      scan1_chunk(cur1s[1], msh, CHUNK, CHUNK, tid, bt1, th1, mem1);
    else if (wid < 14)  emit_rows(cur1s[0], xst, w1r, b1r, 2 * CHUNK, CHUNK, hown, jsl - 1, 6);
    else {
        for (int j = wid - 14; j < ntasks; j += 2)
            cur2_otask(obase + j, 0, obase, lane, msh, W2, b2, c2s);
    }
    __syncthreads();

    // slot2: scan1 c2 | emit c3 (w2-13, 6-way) | cur2 s1 (w14) | scan2 s0 (w15)
    if (tid < 128)      scan1_chunk(cur1s[0], msh, 2 * CHUNK, CHUNK, tid, bt1, th1, mem1);
    else if (wid < 14)  emit_rows(cur1s[1], xst, w1r, b1r, 3 * CHUNK, L3, hown, jsl - 1, 6);
    else if (wid == 14) {
        for (int j = 0; j < ntasks; ++j)
            cur2_otask(obase + j, 1, obase, lane, msh, W2, b2, c2s);
    } else if (lane < ntasks) {
        scan2_stripe<false>(src4, 0, bt2, th2, mem2, out_spk, out_mem);
    }
    __syncthreads();

    // slot3: scan1 c3 | cur2 s2,s3 (w2-13) | scan2 s1 (w15)
    if (tid < 128)      scan1_chunk(cur1s[1], msh, 3 * CHUNK, L3, tid, bt1, th1, mem1);
    else if (wid < 14) {
        const int idx = wid - 2;                 // 0..11
        if (idx < 2 * ntasks)
            cur2_otask(obase + idx % ntasks, 2 + idx / ntasks, obase, lane, msh, W2, b2, c2s);
    } else if (wid == 15 && lane < ntasks) {
        scan2_stripe<false>(src4, 1, bt2, th2, mem2, out_spk, out_mem);
    }
    __syncthreads();

    // slot4: cur2 s4,s5 (w2-13) | scan2 s2,s3 (w15)
    if (wid >= 2 && wid < 14) {
        const int idx = wid - 2;
        if (idx < 2 * ntasks)
            cur2_otask(obase + idx % ntasks, 4 + idx / ntasks, obase, lane, msh, W2, b2, c2s);
    } else if (wid == 15 && lane < ntasks) {
        scan2_stripe<false>(src4, 2, bt2, th2, mem2, out_spk, out_mem);
        scan2_stripe<false>(src4, 3, bt2, th2, mem2, out_spk, out_mem);
    }
    __syncthreads();

    // slot5: scan2 s4, s5+tail (w15) — no trailing barrier
    if (wid == 15 && lane < ntasks) {
        scan2_stripe<false>(src4, 4, bt2, th2, mem2, out_spk, out_mem);
        scan2_stripe<true >(src4, 5, bt2, th2, mem2, out_spk, out_mem);
    }
}

extern "C" void kernel_launch(void* const* d_in, const int* in_sizes, int n_in,
                              void* d_out, int out_size, void* d_ws, size_t ws_size,
                              hipStream_t stream) {
    const float* x     = (const float*)d_in[0];
    const float* W1    = (const float*)d_in[1];
    const float* b1    = (const float*)d_in[2];
    const float* W2    = (const float*)d_in[3];
    const float* b2    = (const float*)d_in[4];
    const float* beta1 = (const float*)d_in[5];
    const float* thr1  = (const float*)d_in[6];
    const float* beta2 = (const float*)d_in[7];
    const float* thr2  = (const float*)d_in[8];
    float* out = (float*)d_out;
    (void)in_sizes; (void)n_in; (void)out_size; (void)d_ws; (void)ws_size;

    snn_fused<<<dim3(B_SZ * 2), dim3(1024), 0, stream>>>(
        x, W1, b1, W2, b2, beta1, thr1, beta2, thr2, out);
}